// Round 6
// baseline (900.934 us; speedup 1.0000x reference)
//
#include <hip/hip_runtime.h>
#include <hip/hip_bf16.h>
#include <math.h>

// LiquidNCA via bf16 MFMA, v4.0 = v3.11 + TWO-STEP FUSION (10 -> 5 launches).
// Dependency: state_{s+2} on the 16x16 core needs state_s on 24x24 (halo-4).
// One launch: stage 24x24 -> step1 delta on 22x22 -> step1 tau/state' on
// 20x20 (computed into registers, barrier, written back into the state
// channels -- no second LDS buffer) -> step2 delta on 18x18 -> step2 tau on
// the 16x16 core -> global store (or fused readout on the last launch).
// Out-of-image state' is automatically zero (delta=0, state=0 -> sn=0).
// Per-pixel arithmetic is bit-identical to v3.11 (same MFMA order/rounding).
// LDS = 576 rows x 80 B = 46080 B -> 3 blocks/CU (= measured occupancy of
// v3.11, so nothing is lost); __launch_bounds__(256,3) caps VGPR <= 170.
// Carried from v3.11: XCD-chunked bijective block swizzle, RNE cvt_pk pack,
// bpermute q-shuffle with zero-A-tail garbage annihilation, interior-block
// fast path, incremental 2D indexing, setprio around MFMA clusters, tau x
// via 10th MFMA from xp8 channels (pad now 4 -> XPP=264), row cache in the
// final stage-C.
// Core concept (R14-verified): mfma(weights, pixels, acc) -> D[channel][pixel]
// (A/B lane layouts are identical), so each lane owns 1 pixel x 4 consecutive
// channels and every epilogue access is one aligned b64.

#define B_   32
#define H_   256
#define W_   256
#define PIT  40                // comb pitch in ushorts (80 B, 16B-aligned)
#define XPP  264               // xp8pad padded dim (window base in [-4, 259])

typedef unsigned short ushort_t;
typedef __attribute__((ext_vector_type(8))) short short8;
typedef __attribute__((ext_vector_type(4))) float float4v;

__device__ __forceinline__ unsigned fbits(float f) {
    union { float f; unsigned u; } v; v.f = f; return v.u;
}
__device__ __forceinline__ ushort_t f2bu(float f) {        // finite-only, RHU
    return (ushort_t)((fbits(f) + 0x8000u) >> 16);
}
__device__ __forceinline__ unsigned pack2(float lo, float hi) {  // RNE, 1 instr
    union { __hip_bfloat162 h; unsigned u; } v;
    v.h = __float22bfloat162_rn(make_float2(lo, hi));
    return v.u;
}
__device__ __forceinline__ float bu2f(ushort_t u) {
    union { unsigned i; float f; } v; v.i = ((unsigned)u) << 16; return v.f;
}
__device__ __forceinline__ float lo2f(unsigned u) {
    union { unsigned i; float f; } v; v.i = u << 16; return v.f;
}
__device__ __forceinline__ float hi2f(unsigned u) {
    union { unsigned i; float f; } v; v.i = u & 0xFFFF0000u; return v.f;
}

// ---------------------------------------------------------------------------
// prep: UNCHANGED from v3.11.
__global__ void prep(
    const float* __restrict__ wp,   // [32][17][9]
    const float* __restrict__ wu1,  // [16][32]
    const float* __restrict__ bu1,  // [16]
    const float* __restrict__ bp,   // [32]
    const float* __restrict__ wu2,  // [16][16]
    const float* __restrict__ wt,   // [16][33][9]
    const float* __restrict__ btc,  // [16]
    const float* __restrict__ bt,   // [16]
    ushort_t* __restrict__ wh1p,    // [5][64][8]  4 pairs + (tap8||x0..8)
    ushort_t* __restrict__ wu2f,    // [64][8]
    ushort_t* __restrict__ wtxf,    // [64][8]  tau x-taps, K: 0..7 used
    ushort_t* __restrict__ wtn,     // [9][64][8]
    float* __restrict__ scal)       // [64] beff | wxh8 | tb | wtx8
{
    __shared__ float Weff[16 * 153];   // [n][c(0..16)][t]
    const int tid = threadIdx.x;

    for (int i = tid; i < 16 * 153; i += 256) {
        int j = i / 153, rem = i % 153, c = rem / 9, t = rem % 9;
        float s = 0.f;
        for (int o = 0; o < 32; ++o)
            s += wu1[j * 32 + o] * wp[o * 153 + c * 9 + t];
        Weff[i] = s;
    }
    if (tid < 16) {
        float s = bu1[tid];
        for (int o = 0; o < 32; ++o) s += wu1[tid * 32 + o] * bp[o];
        scal[tid] = s;                          // beff
    }
    if (tid < 16) scal[32 + tid] = btc[tid] + bt[tid];   // tau bias
    if (tid < 16) scal[48 + tid] = wt[tid * 297 + 8];    // tau tap-8 x weight
    __syncthreads();

    if (tid < 16) scal[16 + tid] = Weff[tid * 153 + 8];   // wxh8 (c=0, tap8)

    // pairs ii=0..3: K = [state@tap2ii (k0..15) || state@tap2ii+1 (k16..31)]
    for (int i = tid; i < 4 * 64 * 8; i += 256) {
        int ii = i >> 9, lane = (i >> 3) & 63, j = i & 7;
        int n = lane & 15, kk = ((lane >> 4) << 3) + j;
        int tap = 2 * ii + (kk >> 4), ch = kk & 15;
        wh1p[i] = f2bu(Weff[n * 153 + (ch + 1) * 9 + tap]);
    }
    // 5th: k<16 -> state@tap8; k=16..23 -> x@tap(k-16); k==24 -> x@tap8; else 0
    for (int i = tid; i < 512; i += 256) {
        int lane = i >> 3, j = i & 7;
        int n = lane & 15, k = ((lane >> 4) << 3) + j;
        float v = 0.f;
        if (k < 16)       v = Weff[n * 153 + (k + 1) * 9 + 8];
        else if (k < 24)  v = Weff[n * 153 + (k - 16)];      // c=0, tap k-16
        else if (k == 24) v = Weff[n * 153 + 8];             // c=0, tap 8
        wh1p[2048 + i] = f2bu(v);
    }
    // wu2f: (k<16) ? wu2[n][k] : 0
    for (int i = tid; i < 512; i += 256) {
        int lane = i >> 3, j = i & 7;
        int n = lane & 15, k = ((lane >> 4) << 3) + j;
        wu2f[i] = (k < 16) ? f2bu(wu2[n * 16 + k]) : (ushort_t)0;
    }
    // wtxf: tau x-tap weights wt[n][0][t], K-slot t = tap (0..7), else 0
    for (int i = tid; i < 512; i += 256) {
        int lane = i >> 3, j = i & 7;
        int n = lane & 15, k = ((lane >> 4) << 3) + j;
        wtxf[i] = (k < 8) ? f2bu(wt[n * 297 + k]) : (ushort_t)0;
    }
    // wtn: A = [delta(16) || state(16)] weights for tau
    for (int i = tid; i < 9 * 64 * 8; i += 256) {
        int t = i / 512, lane = (i / 8) % 64, j = i % 8;
        int n = lane & 15, k = ((lane >> 4) << 3) + j;
        int c = (k < 16) ? (17 + k) : (k - 15);
        wtn[i] = f2bu(wt[n * 297 + c * 9 + t]);
    }
}

// ---------------------------------------------------------------------------
// xp8pad[b][by][bx][8] = bf16 x at taps 0..7 of the 3x3 window based at
// global (by-4, bx-4); out-of-image taps are zero. tap0 = own x.
__global__ __launch_bounds__(256) void precompute_xp8(
    const float* __restrict__ x,     // [B][H][W] fp32
    ushort_t* __restrict__ xp8)      // [B][XPP][XPP][8] bf16
{
    int idx = blockIdx.x * 256 + threadIdx.x;
    if (idx >= B_ * XPP * XPP) return;
    int b  = idx / (XPP * XPP), rem = idx - b * (XPP * XPP);
    int by = rem / XPP, bx = rem - by * XPP;
    int gy = by - 4, gx = bx - 4;                 // window base in image coords
    const float* xb = x + (size_t)b * 65536;
    short8 v;
#pragma unroll
    for (int t = 0; t < 8; ++t) {
        int yy = gy + t / 3, xx = gx + t % 3;
        bool in = ((unsigned)yy < 256u) & ((unsigned)xx < 256u);
        v[t] = in ? (short)f2bu(xb[yy * 256 + xx]) : (short)0;
    }
    *(short8*)(xp8 + (size_t)idx * 8) = v;
}

// ---------------------------------------------------------------------------
// Fused 2-step NCA kernel. comb: 24x24 halo-4 tile, pitch-40 rows
// [delta 0..15 | state 16..31 | xpatch8 32..39].
__global__ __launch_bounds__(256, 3) void nca_step2(
    const ushort_t* __restrict__ stIn,   // [B][H][W][16] bf16 (unused if first)
    ushort_t* __restrict__ stOut,        // [B][H][W][16] bf16 (unused if last)
    const ushort_t* __restrict__ xp8g,   // [B][XPP][XPP][8] bf16
    const ushort_t* __restrict__ wh1p,
    const ushort_t* __restrict__ wu2f,
    const ushort_t* __restrict__ wtxf,
    const ushort_t* __restrict__ wtn,
    const float* __restrict__ scal,      // [64] beff | wxh8 | tb | wtx8
    const float* __restrict__ bu2G,
    const float* __restrict__ wrd,       // w_read [16]
    const float* __restrict__ brd,       // b_read [1]
    float* __restrict__ outg,            // [B][H][W] fp32 (used if last)
    int first, int last)
{
    __shared__ ushort_t comb[576 * PIT]; // 24x24 halo-4; 46080 B -> 3 blk/CU

    const int tid  = threadIdx.x;
    const int w    = tid >> 6, lane = tid & 63;
    const int m    = lane & 15, q = lane >> 4;
    const int och  = q * 4;
    // XCD-chunked bijective swizzle (8192 = 8 XCD x 1024)
    const int flat = ((int)blockIdx.z << 8) | ((int)blockIdx.y << 4) | (int)blockIdx.x;
    const int nf   = ((flat & 7) << 10) | (flat >> 3);
    const int bxi  = nf & 15, byi = (nf >> 4) & 15, bzi = nf >> 8;
    const int gx0  = bxi * 16, gy0 = byi * 16;
    const size_t pb = (size_t)bzi * 65536;
    const size_t xpb = (size_t)bzi * (XPP * XPP);
    const short8 z8 = {0, 0, 0, 0, 0, 0, 0, 0};
    const float4v z4 = {0.f, 0.f, 0.f, 0.f};

    // full 24x24 stage + both delta regions in-image?
    const bool interior = (bxi >= 1) & (bxi <= 14) & (byi >= 1) & (byi <= 14);

    // per-wave weight fragments (MFMA A operands)
    short8 wh1r[5], wtnr[9];
#pragma unroll
    for (int i = 0; i < 5; ++i) wh1r[i] = *(const short8*)(wh1p + (i * 64 + lane) * 8);
#pragma unroll
    for (int t = 0; t < 9; ++t) wtnr[t] = *(const short8*)(wtn + (t * 64 + lane) * 8);
    const short8 wu2r = *(const short8*)(wu2f + lane * 8);
    const short8 wtxr = *(const short8*)(wtxf + lane * 8);

    float4v beff4, bu24, wr4, tb4, wtx84;
#pragma unroll
    for (int r = 0; r < 4; ++r) {
        beff4[r] = scal[och + r];
        tb4[r]   = scal[32 + och + r];
        wtx84[r] = scal[48 + och + r];
        bu24[r]  = bu2G[och + r];
        wr4[r]   = wrd[och + r];
    }
    const float br = brd[0];

    // paired-tap B-read offsets (tap = 2*ii + (q>>1)), grid width 24
    const int sel = q >> 1;
    int offp[4];
#pragma unroll
    for (int ii = 0; ii < 4; ++ii) {
        int tA = 2 * ii, tB = 2 * ii + 1;
        int oA = ((tA / 3) * 24 + (tA % 3)) * PIT;
        int oB = ((tB / 3) * 24 + (tB % 3)) * PIT;
        offp[ii] = sel ? oB : oA;
    }
    const int chOff = 16 + (q & 1) * 8;
    const int t8off = (2 * 24 + 2) * PIT;
    const int off5  = (q == 0) ? (t8off + 16) : (q == 1) ? (t8off + 24)
                    : (q == 2) ? 32 : (t8off + 32);
    const int bpA = ((m + (q << 5)) & 63) << 2;

    // ---- stage A: stage 24x24 state ch16..31 + xpatch8 ch32..39 ------------
    if (interior & (first == 0)) {
        for (int p = tid; p < 576; p += 256) {
            int ry = p / 24, rx = p - ry * 24;
            ushort_t* row = comb + p * PIT;
            const ushort_t* sp = stIn
                + (pb + (size_t)(gy0 + ry - 4) * 256 + (gx0 + rx - 4)) * 16;
            *(short8*)(row + 16) = *(const short8*)(sp);
            *(short8*)(row + 24) = *(const short8*)(sp + 8);
            *(short8*)(row + 32) = *(const short8*)(
                xp8g + (xpb + (size_t)(gy0 + ry) * XPP + (gx0 + rx)) * 8);
        }
    } else {
        for (int p = tid; p < 576; p += 256) {
            int ry = p / 24, rx = p - ry * 24;
            int gy = gy0 + ry - 4, gx = gx0 + rx - 4;
            ushort_t* row = comb + p * PIT;
            bool in = ((unsigned)gy < 256u) & ((unsigned)gx < 256u);
            if (in && !first) {
                const ushort_t* sp = stIn + (pb + gy * 256 + gx) * 16;
                *(short8*)(row + 16) = *(const short8*)(sp);
                *(short8*)(row + 24) = *(const short8*)(sp + 8);
            } else {
                *(short8*)(row + 16) = z8; *(short8*)(row + 24) = z8;
            }
            *(short8*)(row + 32) = *(const short8*)(
                xp8g + (xpb + (size_t)(gy0 + ry) * XPP + (gx0 + rx)) * 8);
        }
    }
    __syncthreads();

    // ---- step1 stage B: h1+up2 -> delta on 22x22 (abase rows/cols 0..21) ---
    {
        int raw = w * 16 + m;                    // index in 22x22 region
        int py = raw / 22, px = raw - (raw / 22) * 22;
        for (int i = 0; i < 8; ++i) {
            int g = w + 4 * i; if (g >= 31) break;
            bool vld = raw < 484;
            int pyc = vld ? py : 21, pxc = vld ? px : 21;
            const ushort_t* abase = comb + (pyc * 24 + pxc) * PIT;
            float4v acc = z4;
            __builtin_amdgcn_s_setprio(1);
#pragma unroll
            for (int ii = 0; ii < 4; ++ii) {
                short8 b = *(const short8*)(abase + offp[ii] + chOff);
                acc = __builtin_amdgcn_mfma_f32_16x16x32_bf16(wh1r[ii], b, acc, 0, 0, 0);
            }
            {
                short8 b = *(const short8*)(abase + off5);
                acc = __builtin_amdgcn_mfma_f32_16x16x32_bf16(wh1r[4], b, acc, 0, 0, 0);
            }
            __builtin_amdgcn_s_setprio(0);
            uint2 hv;
            hv.x = pack2(fmaxf(acc[0] + beff4[0], 0.f),
                         fmaxf(acc[1] + beff4[1], 0.f));
            hv.y = pack2(fmaxf(acc[2] + beff4[2], 0.f),
                         fmaxf(acc[3] + beff4[3], 0.f));
            union { int i4[4]; short8 s8; } bb;
            bb.i4[0] = __builtin_amdgcn_ds_bpermute(bpA,      (int)hv.x);
            bb.i4[1] = __builtin_amdgcn_ds_bpermute(bpA,      (int)hv.y);
            bb.i4[2] = __builtin_amdgcn_ds_bpermute(bpA + 64, (int)hv.x);
            bb.i4[3] = __builtin_amdgcn_ds_bpermute(bpA + 64, (int)hv.y);
            float4v d = __builtin_amdgcn_mfma_f32_16x16x32_bf16(wu2r, bb.s8, z4, 0, 0, 0);
            uint2 dv;
            dv.x = pack2(d[0] + bu24[0], d[1] + bu24[1]);
            dv.y = pack2(d[2] + bu24[2], d[3] + bu24[3]);
            if (!interior) {
                int gy = gy0 + pyc - 3, gx = gx0 + pxc - 3;  // pixel global
                bool im = ((unsigned)gy < 256u) & ((unsigned)gx < 256u);
                if (!im) { dv.x = 0u; dv.y = 0u; }
            }
            if (vld)
                *(uint2*)(comb + ((pyc + 1) * 24 + (pxc + 1)) * PIT + och) = dv;
            raw += 64; px += 20; py += 2;
            if (px >= 22) { px -= 22; py += 1; }
        }
    }
    __syncthreads();

    // ---- step1 stage C: tau on 20x20 -> state' into registers --------------
    uint2 sreg[7];
    {
        int idx = w * 16 + m;                    // index in 20x20 region
        int r = idx / 20, c = idx - (idx / 20) * 20;
#pragma unroll
        for (int i = 0; i < 7; ++i) {
            bool vld = idx < 400;
            int rc = vld ? r : 19, cc = vld ? c : 19;
            const ushort_t* cb = comb + ((rc + 1) * 24 + (cc + 1)) * PIT;
            float4v acc = z4;
            __builtin_amdgcn_s_setprio(1);
#pragma unroll
            for (int t = 0; t < 9; ++t) {
                short8 b = *(const short8*)(cb + ((t / 3) * 24 + (t % 3)) * PIT + q * 8);
                acc = __builtin_amdgcn_mfma_f32_16x16x32_bf16(wtnr[t], b, acc, 0, 0, 0);
            }
            {
                short8 bx = *(const short8*)(cb + 32);
                acc = __builtin_amdgcn_mfma_f32_16x16x32_bf16(wtxr, bx, acc, 0, 0, 0);
            }
            __builtin_amdgcn_s_setprio(0);
            const ushort_t* cpx = comb + ((rc + 2) * 24 + (cc + 2)) * PIT;
            float x8c = bu2f(comb[((rc + 3) * 24 + (cc + 3)) * PIT + 32]);
            uint2 su = *(const uint2*)(cpx + 16 + och);
            uint2 du = *(const uint2*)(cpx + och);
            float sold[4] = { lo2f(su.x), hi2f(su.x), lo2f(su.y), hi2f(su.y) };
            float dvv[4]  = { lo2f(du.x), hi2f(du.x), lo2f(du.y), hi2f(du.y) };
            float sn[4];
#pragma unroll
            for (int rr = 0; rr < 4; ++rr) {
                float tl  = acc[rr] + tb4[rr] + x8c * wtx84[rr];
                float e   = __expf(-tl);
                float bta = __builtin_amdgcn_rcpf(1.f + e);
                bta = fminf(fmaxf(bta, 0.01f), 0.99f);
                sn[rr] = dvv[rr] + bta * (sold[rr] - dvv[rr]);
            }
            sreg[i].x = pack2(sn[0], sn[1]);
            sreg[i].y = pack2(sn[2], sn[3]);
            idx += 64; c += 4; r += 3;
            if (c >= 20) { c -= 20; r += 1; }
        }
    }
    __syncthreads();
    // writeback state' into ch16..31 rows/cols 2..21
    {
        int idx = w * 16 + m;
        int r = idx / 20, c = idx - (idx / 20) * 20;
#pragma unroll
        for (int i = 0; i < 7; ++i) {
            if (idx < 400)
                *(uint2*)(comb + ((r + 2) * 24 + (c + 2)) * PIT + 16 + och) = sreg[i];
            idx += 64; c += 4; r += 3;
            if (c >= 20) { c -= 20; r += 1; }
        }
    }
    __syncthreads();

    // ---- step2 stage B: h1+up2 -> delta on 18x18 (abase +2 offset) ---------
    {
        int raw = w * 16 + m;                    // index in 18x18 region
        int py = raw / 18, px = raw - (raw / 18) * 18;
        for (int i = 0; i < 6; ++i) {
            int g = w + 4 * i; if (g >= 21) break;
            bool vld = raw < 324;
            int pyc = vld ? py : 17, pxc = vld ? px : 17;
            const ushort_t* abase = comb + ((pyc + 2) * 24 + (pxc + 2)) * PIT;
            float4v acc = z4;
            __builtin_amdgcn_s_setprio(1);
#pragma unroll
            for (int ii = 0; ii < 4; ++ii) {
                short8 b = *(const short8*)(abase + offp[ii] + chOff);
                acc = __builtin_amdgcn_mfma_f32_16x16x32_bf16(wh1r[ii], b, acc, 0, 0, 0);
            }
            {
                short8 b = *(const short8*)(abase + off5);
                acc = __builtin_amdgcn_mfma_f32_16x16x32_bf16(wh1r[4], b, acc, 0, 0, 0);
            }
            __builtin_amdgcn_s_setprio(0);
            uint2 hv;
            hv.x = pack2(fmaxf(acc[0] + beff4[0], 0.f),
                         fmaxf(acc[1] + beff4[1], 0.f));
            hv.y = pack2(fmaxf(acc[2] + beff4[2], 0.f),
                         fmaxf(acc[3] + beff4[3], 0.f));
            union { int i4[4]; short8 s8; } bb;
            bb.i4[0] = __builtin_amdgcn_ds_bpermute(bpA,      (int)hv.x);
            bb.i4[1] = __builtin_amdgcn_ds_bpermute(bpA,      (int)hv.y);
            bb.i4[2] = __builtin_amdgcn_ds_bpermute(bpA + 64, (int)hv.x);
            bb.i4[3] = __builtin_amdgcn_ds_bpermute(bpA + 64, (int)hv.y);
            float4v d = __builtin_amdgcn_mfma_f32_16x16x32_bf16(wu2r, bb.s8, z4, 0, 0, 0);
            uint2 dv;
            dv.x = pack2(d[0] + bu24[0], d[1] + bu24[1]);
            dv.y = pack2(d[2] + bu24[2], d[3] + bu24[3]);
            if (!interior) {
                int gy = gy0 + pyc - 1, gx = gx0 + pxc - 1;  // pixel global
                bool im = ((unsigned)gy < 256u) & ((unsigned)gx < 256u);
                if (!im) { dv.x = 0u; dv.y = 0u; }
            }
            if (vld)
                *(uint2*)(comb + ((pyc + 3) * 24 + (pxc + 3)) * PIT + och) = dv;
            raw += 64; px += 10; py += 3;
            if (px >= 18) { px -= 18; py += 1; }
        }
    }
    __syncthreads();

    // ---- step2 stage C: tau on 16x16 core (+4 offset), row cache -----------
    {
        const int w4 = w * 4;
#define LDROW(rr, dx) (*(const short8*)(comb + ((rr) * 24 + (m + 3 + (dx))) * PIT + q * 8))
        short8 Ta0 = LDROW(w4 + 3, 0), Ta1 = LDROW(w4 + 3, 1), Ta2 = LDROW(w4 + 3, 2);
        short8 Tb0 = LDROW(w4 + 4, 0), Tb1 = LDROW(w4 + 4, 1), Tb2 = LDROW(w4 + 4, 2);
#pragma unroll
        for (int i = 0; i < 4; ++i) {
            int g = w4 + i;                      // core row; pixel col = m
            short8 Tc0 = LDROW(g + 5, 0), Tc1 = LDROW(g + 5, 1), Tc2 = LDROW(g + 5, 2);
            short8 bx = *(const short8*)(comb + ((g + 3) * 24 + (m + 3)) * PIT + 32);
            const ushort_t* cpx = comb + ((g + 4) * 24 + (m + 4)) * PIT;
            float x8c = bu2f(comb[((g + 5) * 24 + (m + 5)) * PIT + 32]);
            uint2 su = *(const uint2*)(cpx + 16 + och);        // state' och..+3
            uint2 du = *(const uint2*)(cpx + och);             // delta
            float4v acc = z4;
            __builtin_amdgcn_s_setprio(1);
            acc = __builtin_amdgcn_mfma_f32_16x16x32_bf16(wtnr[0], Ta0, acc, 0, 0, 0);
            acc = __builtin_amdgcn_mfma_f32_16x16x32_bf16(wtnr[1], Ta1, acc, 0, 0, 0);
            acc = __builtin_amdgcn_mfma_f32_16x16x32_bf16(wtnr[2], Ta2, acc, 0, 0, 0);
            acc = __builtin_amdgcn_mfma_f32_16x16x32_bf16(wtnr[3], Tb0, acc, 0, 0, 0);
            acc = __builtin_amdgcn_mfma_f32_16x16x32_bf16(wtnr[4], Tb1, acc, 0, 0, 0);
            acc = __builtin_amdgcn_mfma_f32_16x16x32_bf16(wtnr[5], Tb2, acc, 0, 0, 0);
            acc = __builtin_amdgcn_mfma_f32_16x16x32_bf16(wtnr[6], Tc0, acc, 0, 0, 0);
            acc = __builtin_amdgcn_mfma_f32_16x16x32_bf16(wtnr[7], Tc1, acc, 0, 0, 0);
            acc = __builtin_amdgcn_mfma_f32_16x16x32_bf16(wtnr[8], Tc2, acc, 0, 0, 0);
            acc = __builtin_amdgcn_mfma_f32_16x16x32_bf16(wtxr,   bx,  acc, 0, 0, 0);
            __builtin_amdgcn_s_setprio(0);
            const size_t pix = pb + (size_t)(gy0 + g) * 256 + gx0 + m;
            float sold[4] = { lo2f(su.x), hi2f(su.x), lo2f(su.y), hi2f(su.y) };
            float dvv[4]  = { lo2f(du.x), hi2f(du.x), lo2f(du.y), hi2f(du.y) };
            float sn[4];
#pragma unroll
            for (int rr = 0; rr < 4; ++rr) {
                float tl  = acc[rr] + tb4[rr] + x8c * wtx84[rr];
                float e   = __expf(-tl);
                float bta = __builtin_amdgcn_rcpf(1.f + e);
                bta = fminf(fmaxf(bta, 0.01f), 0.99f);
                sn[rr] = dvv[rr] + bta * (sold[rr] - dvv[rr]);
            }
            if (!last) {
                uint2 o;
                o.x = pack2(sn[0], sn[1]); o.y = pack2(sn[2], sn[3]);
                *(uint2*)(stOut + pix * 16 + och) = o;
            } else {
                float v = sn[0] * wr4[0] + sn[1] * wr4[1]
                        + sn[2] * wr4[2] + sn[3] * wr4[3];
                v += __shfl_xor(v, 16);
                v += __shfl_xor(v, 32);
                if (q == 0) {
                    float eo = __expf(-(v + br));
                    outg[pix] = __builtin_amdgcn_rcpf(1.f + eo);
                }
            }
            Ta0 = Tb0; Ta1 = Tb1; Ta2 = Tb2;
            Tb0 = Tc0; Tb1 = Tc1; Tb2 = Tc2;
        }
#undef LDROW
    }
}

// ---------------------------------------------------------------------------
extern "C" void kernel_launch(void* const* d_in, const int* in_sizes, int n_in,
                              void* d_out, int out_size, void* d_ws, size_t ws_size,
                              hipStream_t stream)
{
    const float* x          = (const float*)d_in[0];
    const float* w_perceive = (const float*)d_in[1];
    const float* b_perceive = (const float*)d_in[2];
    const float* w_up1      = (const float*)d_in[3];
    const float* b_up1      = (const float*)d_in[4];
    const float* w_up2      = (const float*)d_in[5];
    const float* b_up2      = (const float*)d_in[6];
    const float* w_tau      = (const float*)d_in[7];
    const float* b_tau_conv = (const float*)d_in[8];
    const float* b_tau      = (const float*)d_in[9];
    const float* w_read     = (const float*)d_in[10];
    const float* b_read     = (const float*)d_in[11];
    // d_in[12] = n_steps = 10 (host-known; 5 fused launches)
    float* out = (float*)d_out;

    const size_t stateElems = (size_t)B_ * H_ * W_ * 16;     // 33,554,432 bf16
    const size_t xp8Elems   = (size_t)B_ * XPP * XPP * 8;    // 17,842,176 bf16

    ushort_t* stA  = (ushort_t*)d_ws;
    ushort_t* stB  = stA + stateElems;
    ushort_t* xp8g = stB + stateElems;         // 35.7 MB
    ushort_t* wh1p = xp8g + xp8Elems;          // 2560
    ushort_t* wu2f = wh1p + 2560;              // 512
    ushort_t* wtxf = wu2f + 512;               // 512
    ushort_t* wtn  = wtxf + 512;               // 4608
    float*    scal = (float*)(wtn + 4608);     // 64 floats

    const size_t needBytes = (2 * stateElems + xp8Elems
                              + 2560 + 512 + 512 + 4608) * sizeof(ushort_t)
                           + 64 * sizeof(float);
    if (ws_size < needBytes) return;

    prep<<<dim3(1), dim3(256), 0, stream>>>(
        w_perceive, w_up1, b_up1, b_perceive, w_up2, w_tau,
        b_tau_conv, b_tau, wh1p, wu2f, wtxf, wtn, scal);
    precompute_xp8<<<dim3((B_ * XPP * XPP + 255) / 256), dim3(256), 0, stream>>>(
        x, xp8g);

    ushort_t* cur = stA;
    ushort_t* nxt = stB;
    for (int s = 0; s < 5; ++s) {             // 5 fused launches = 10 NCA steps
        nca_step2<<<dim3(16, 16, 32), dim3(256), 0, stream>>>(
            cur, nxt, xp8g, wh1p, wu2f, wtxf, wtn, scal, b_up2,
            w_read, b_read, out, (s == 0) ? 1 : 0, (s == 4) ? 1 : 0);
        ushort_t* t = cur; cur = nxt; nxt = t;
    }
}

// Round 8
// 708.757 us; speedup vs baseline: 1.2711x; 1.2711x over previous
//
#include <hip/hip_runtime.h>
#include <hip/hip_bf16.h>
#include <math.h>

// LiquidNCA via bf16 MFMA, v3.12 = v3.10 (the 715 us best) + ZERO-SHUFFLE up2.
// (R7 resubmission: previous round's bench was an infra failure -- container
// acquisition failed twice; the kernel never ran.)
// R6's 2-step fusion REVERTED (halo recompute +37% loop work beat the launch
// savings; 188 us fused vs 153 us for two unfused steps).
// New in v3.12: the stage-B D->B cross-lane exchange (4x ds_bpermute + waits
// per iteration) is deleted via K-slot remapping. In mfma(A,B), A and B are
// both indexed by k, so any k-permutation applied to BOTH is identity on the
// result. Lane (m,q) already holds h1 channels 4q..4q+3 of pixel m (hv), and
// the B lane-layout has lane (m,q) supply k-slots 8q..8q+7. So wu2f places
// channel 4a+b at k-slot 8a+b (b<4; zero at b>=4), and every lane's B-frag
// is just {hv.x, hv.y, 0, 0}: no bpermute, no masking, each channel summed
// exactly once from exactly the lane that computed it.
// Carried from v3.10: stage-C tap-row register cache (3 fresh b128/iter),
// stage-B tap-8 folded into 5th MFMA at K=24, interior-block fast path,
// incremental py/px, setprio around conv MFMA clusters, RHU pack, tau x via
// 10th stage-C MFMA + scalar tap-8 epilogue, no tx tensor (163 MB working
// set fits L3), LDS = comb only = 32000 B.
// Core concept (R14-verified): mfma(weights, pixels, acc) -> D[channel][pixel]
// (A/B lane layouts are identical), so each lane owns 1 pixel x 4 consecutive
// channels and every epilogue access is one aligned b64.

#define B_   32
#define H_   256
#define W_   256
#define PIT  40                // comb pitch in ushorts (80 B, 16B-aligned)
#define XPP  260               // xp8pad padded dim (base gy in [-2, 257])

typedef unsigned short ushort_t;
typedef __attribute__((ext_vector_type(8))) short short8;
typedef __attribute__((ext_vector_type(4))) float float4v;

__device__ __forceinline__ unsigned fbits(float f) {
    union { float f; unsigned u; } v; v.f = f; return v.u;
}
__device__ __forceinline__ ushort_t f2bu(float f) {        // finite-only, RHU
    return (ushort_t)((fbits(f) + 0x8000u) >> 16);
}
__device__ __forceinline__ unsigned pack2(float lo, float hi) {
    return ((fbits(hi) + 0x8000u) & 0xFFFF0000u) | ((fbits(lo) + 0x8000u) >> 16);
}
__device__ __forceinline__ float bu2f(ushort_t u) {
    union { unsigned i; float f; } v; v.i = ((unsigned)u) << 16; return v.f;
}
__device__ __forceinline__ float lo2f(unsigned u) {
    union { unsigned i; float f; } v; v.i = u << 16; return v.f;
}
__device__ __forceinline__ float hi2f(unsigned u) {
    union { unsigned i; float f; } v; v.i = u & 0xFFFF0000u; return v.f;
}

// ---------------------------------------------------------------------------
// prep: v3.10 with one change -- wu2f K-slot remap for the zero-shuffle up2:
//   wu2f[n][k], k = 8a+b: (b < 4) ? wu2[n][4a+b] : 0.
__global__ void prep(
    const float* __restrict__ wp,   // [32][17][9]
    const float* __restrict__ wu1,  // [16][32]
    const float* __restrict__ bu1,  // [16]
    const float* __restrict__ bp,   // [32]
    const float* __restrict__ wu2,  // [16][16]
    const float* __restrict__ wt,   // [16][33][9]
    const float* __restrict__ btc,  // [16]
    const float* __restrict__ bt,   // [16]
    ushort_t* __restrict__ wh1p,    // [5][64][8]  4 pairs + (tap8||x0..8)
    ushort_t* __restrict__ wu2f,    // [64][8]
    ushort_t* __restrict__ wtxf,    // [64][8]  tau x-taps, K: 0..7 used
    ushort_t* __restrict__ wtn,     // [9][64][8]
    float* __restrict__ scal)       // [64] beff | wxh8 | tb | wtx8
{
    __shared__ float Weff[16 * 153];   // [n][c(0..16)][t]
    const int tid = threadIdx.x;

    for (int i = tid; i < 16 * 153; i += 256) {
        int j = i / 153, rem = i % 153, c = rem / 9, t = rem % 9;
        float s = 0.f;
        for (int o = 0; o < 32; ++o)
            s += wu1[j * 32 + o] * wp[o * 153 + c * 9 + t];
        Weff[i] = s;
    }
    if (tid < 16) {
        float s = bu1[tid];
        for (int o = 0; o < 32; ++o) s += wu1[tid * 32 + o] * bp[o];
        scal[tid] = s;                          // beff
    }
    if (tid < 16) scal[32 + tid] = btc[tid] + bt[tid];   // tau bias
    if (tid < 16) scal[48 + tid] = wt[tid * 297 + 8];    // tau tap-8 x weight
    __syncthreads();

    if (tid < 16) scal[16 + tid] = Weff[tid * 153 + 8];   // wxh8 (c=0, tap8)

    // pairs ii=0..3: K = [state@tap2ii (k0..15) || state@tap2ii+1 (k16..31)]
    for (int i = tid; i < 4 * 64 * 8; i += 256) {
        int ii = i >> 9, lane = (i >> 3) & 63, j = i & 7;
        int n = lane & 15, kk = ((lane >> 4) << 3) + j;
        int tap = 2 * ii + (kk >> 4), ch = kk & 15;
        wh1p[i] = f2bu(Weff[n * 153 + (ch + 1) * 9 + tap]);
    }
    // 5th: k<16 -> state@tap8; k=16..23 -> x@tap(k-16); k==24 -> x@tap8; else 0
    for (int i = tid; i < 512; i += 256) {
        int lane = i >> 3, j = i & 7;
        int n = lane & 15, k = ((lane >> 4) << 3) + j;
        float v = 0.f;
        if (k < 16)       v = Weff[n * 153 + (k + 1) * 9 + 8];
        else if (k < 24)  v = Weff[n * 153 + (k - 16)];      // c=0, tap k-16
        else if (k == 24) v = Weff[n * 153 + 8];             // c=0, tap 8
        wh1p[2048 + i] = f2bu(v);
    }
    // wu2f (zero-shuffle remap): k = 8a+b -> (b<4) ? wu2[n][4a+b] : 0
    for (int i = tid; i < 512; i += 256) {
        int lane = i >> 3, j = i & 7;
        int n = lane & 15, k = ((lane >> 4) << 3) + j;
        int a = k >> 3, b = k & 7;
        wu2f[i] = (b < 4) ? f2bu(wu2[n * 16 + 4 * a + b]) : (ushort_t)0;
    }
    // wtxf: tau x-tap weights wt[n][0][t], K-slot t = tap (0..7), else 0
    for (int i = tid; i < 512; i += 256) {
        int lane = i >> 3, j = i & 7;
        int n = lane & 15, k = ((lane >> 4) << 3) + j;
        wtxf[i] = (k < 8) ? f2bu(wt[n * 297 + k]) : (ushort_t)0;
    }
    // wtn: A = [delta(16) || state(16)] weights for tau
    for (int i = tid; i < 9 * 64 * 8; i += 256) {
        int t = i / 512, lane = (i / 8) % 64, j = i % 8;
        int n = lane & 15, k = ((lane >> 4) << 3) + j;
        int c = (k < 16) ? (17 + k) : (k - 15);
        wtn[i] = f2bu(wt[n * 297 + c * 9 + t]);
    }
}

// ---------------------------------------------------------------------------
// xp8pad[b][by][bx][8] = bf16 x at taps 0..7 of the 3x3 window based at
// global (by-2, bx-2); out-of-image taps are zero. tap0 = own x.
__global__ __launch_bounds__(256) void precompute_xp8(
    const float* __restrict__ x,     // [B][H][W] fp32
    ushort_t* __restrict__ xp8)      // [B][XPP][XPP][8] bf16
{
    int idx = blockIdx.x * 256 + threadIdx.x;
    if (idx >= B_ * XPP * XPP) return;
    int b  = idx / (XPP * XPP), rem = idx - b * (XPP * XPP);
    int by = rem / XPP, bx = rem - by * XPP;
    int gy = by - 2, gx = bx - 2;                 // window base in image coords
    const float* xb = x + (size_t)b * 65536;
    short8 v;
#pragma unroll
    for (int t = 0; t < 8; ++t) {
        int yy = gy + t / 3, xx = gx + t % 3;
        bool in = ((unsigned)yy < 256u) & ((unsigned)xx < 256u);
        v[t] = in ? (short)f2bu(xb[yy * 256 + xx]) : (short)0;
    }
    *(short8*)(xp8 + (size_t)idx * 8) = v;
}

// ---------------------------------------------------------------------------
__global__ __launch_bounds__(256) void nca_step(
    const ushort_t* __restrict__ stIn,   // [B][H][W][16] bf16 (unused if first)
    ushort_t* __restrict__ stOut,        // [B][H][W][16] bf16 (unused if last)
    const ushort_t* __restrict__ xp8g,   // [B][XPP][XPP][8] bf16
    const ushort_t* __restrict__ wh1p,
    const ushort_t* __restrict__ wu2f,
    const ushort_t* __restrict__ wtxf,
    const ushort_t* __restrict__ wtn,
    const float* __restrict__ scal,      // [64] beff | wxh8 | tb | wtx8
    const float* __restrict__ bu2G,
    const float* __restrict__ wrd,       // w_read [16]
    const float* __restrict__ brd,       // b_read [1]
    float* __restrict__ outg,            // [B][H][W] fp32 (used if last)
    int first, int last)
{
    __shared__ ushort_t comb[400 * PIT]; // 20x20 halo-2; LDS = 32000 B

    const int tid  = threadIdx.x;
    const int w    = tid >> 6, lane = tid & 63;
    const int m    = lane & 15, q = lane >> 4;
    const int och  = q * 4;              // base out-channel of this lane's D rows
    const int gx0  = blockIdx.x * 16, gy0 = blockIdx.y * 16;
    const size_t pb = (size_t)blockIdx.z * 65536;
    const size_t xpb = (size_t)blockIdx.z * (XPP * XPP);
    const short8 z8 = {0, 0, 0, 0, 0, 0, 0, 0};
    const float4v z4 = {0.f, 0.f, 0.f, 0.f};

    // all staged rows / h1 pixels / delta pixels in-image for this block?
    const bool interior = (blockIdx.x >= 1) & (blockIdx.x <= 14)
                        & (blockIdx.y >= 1) & (blockIdx.y <= 14);

    // per-wave weight fragments (used as MFMA *A* operands)
    short8 wh1r[5], wtnr[9];
#pragma unroll
    for (int i = 0; i < 5; ++i) wh1r[i] = *(const short8*)(wh1p + (i * 64 + lane) * 8);
#pragma unroll
    for (int t = 0; t < 9; ++t) wtnr[t] = *(const short8*)(wtn + (t * 64 + lane) * 8);
    const short8 wu2r = *(const short8*)(wu2f + lane * 8);
    const short8 wtxr = *(const short8*)(wtxf + lane * 8);

    // per-lane channel-quad biases (channels och..och+3)
    float4v beff4, bu24, wr4, tb4, wtx84;
#pragma unroll
    for (int r = 0; r < 4; ++r) {
        beff4[r] = scal[och + r];
        tb4[r]   = scal[32 + och + r];
        wtx84[r] = scal[48 + och + r];
        bu24[r]  = bu2G[och + r];
        wr4[r]   = wrd[och + r];
    }
    const float br = brd[0];

    // per-lane paired-tap B-read offsets (tap = 2*ii + (q>>1))
    const int sel = q >> 1;
    int offp[4];
#pragma unroll
    for (int ii = 0; ii < 4; ++ii) {
        int tA = 2 * ii, tB = 2 * ii + 1;
        int oA = ((tA / 3) * 20 + (tA % 3)) * PIT;
        int oB = ((tB / 3) * 20 + (tB % 3)) * PIT;
        offp[ii] = sel ? oB : oA;
    }
    const int chOff = 16 + (q & 1) * 8;
    const int t8off = (2 * 20 + 2) * PIT;
    // 5th-MFMA B offsets: q=0/1 -> state@tap8 (k0..15); q=2 -> x taps0..7
    // (k16..23); q=3 -> chunk4 of row (py+2,px+2): j=0 = x@tap8 (k24).
    const int off5  = (q == 0) ? (t8off + 16) : (q == 1) ? (t8off + 24)
                    : (q == 2) ? 32 : (t8off + 32);

    // ---- stage A: stage state ch16..31 + xpatch8 ch32..39 (coalesced) ------
    if (interior & (first == 0)) {
        for (int p = tid; p < 400; p += 256) {
            int ry = p / 20, rx = p - ry * 20;
            ushort_t* row = comb + p * PIT;
            const ushort_t* sp = stIn
                + (pb + (size_t)(gy0 + ry - 2) * 256 + (gx0 + rx - 2)) * 16;
            *(short8*)(row + 16) = *(const short8*)(sp);
            *(short8*)(row + 24) = *(const short8*)(sp + 8);
            *(short8*)(row + 32) = *(const short8*)(
                xp8g + (xpb + (size_t)(gy0 + ry) * XPP + (gx0 + rx)) * 8);
        }
    } else {
        for (int p = tid; p < 400; p += 256) {
            int ry = p / 20, rx = p - ry * 20;
            int gy = gy0 + ry - 2, gx = gx0 + rx - 2;
            ushort_t* row = comb + p * PIT;
            bool in = ((unsigned)gy < 256u) & ((unsigned)gx < 256u);
            if (in && !first) {
                const ushort_t* sp = stIn + (pb + gy * 256 + gx) * 16;
                *(short8*)(row + 16) = *(const short8*)(sp);
                *(short8*)(row + 24) = *(const short8*)(sp + 8);
            } else {
                *(short8*)(row + 16) = z8; *(short8*)(row + 24) = z8;
            }
            *(short8*)(row + 32) = *(const short8*)(
                xp8g + (xpb + (size_t)(gy0 + ry) * XPP + (gx0 + rx)) * 8);
        }
    }
    __syncthreads();

    // ---- stage B: 5-MFMA h1 conv (D[ch][pix]) -> up2 -> inline delta -------
    {
        int raw = w * 16 + m;                    // pixel index for i=0
        int py = raw / 18, px = raw - (raw / 18) * 18;
        for (int i = 0; i < 6; ++i) {
            int g = w + 4 * i; if (g >= 21) break;
            bool vld = raw < 324;
            int pyc = vld ? py : 17, pxc = vld ? px : 17;
            const ushort_t* abase = comb + (pyc * 20 + pxc) * PIT;
            float4v acc = z4;
            __builtin_amdgcn_s_setprio(1);
#pragma unroll
            for (int ii = 0; ii < 4; ++ii) {
                short8 b = *(const short8*)(abase + offp[ii] + chOff);
                acc = __builtin_amdgcn_mfma_f32_16x16x32_bf16(wh1r[ii], b, acc, 0, 0, 0);
            }
            {   // 5th: [state@tap8 || x@taps0..7 || x@tap8 || 0]
                short8 b = *(const short8*)(abase + off5);
                acc = __builtin_amdgcn_mfma_f32_16x16x32_bf16(wh1r[4], b, acc, 0, 0, 0);
            }
            __builtin_amdgcn_s_setprio(0);
            // epilogue: this lane owns pixel (pyc,pxc), channels och..och+3
            uint2 hv;
            {
                float h0 = fmaxf(acc[0] + beff4[0], 0.f);
                float h1 = fmaxf(acc[1] + beff4[1], 0.f);
                float h2 = fmaxf(acc[2] + beff4[2], 0.f);
                float h3 = fmaxf(acc[3] + beff4[3], 0.f);
                hv.x = pack2(h0, h1); hv.y = pack2(h2, h3);
            }
            // ZERO-SHUFFLE up2: lane (m,q) supplies B k-slots 8q..8q+7; wu2f
            // places channel 4q+jj at k-slot 8q+jj (jj<4) and 0 at jj>=4, so
            // this lane's own hv IS its B-fragment. Each channel is summed
            // exactly once (from the lane that computed it). No bpermute.
            union { unsigned u4[4]; short8 s8; } bb;
            bb.u4[0] = hv.x; bb.u4[1] = hv.y; bb.u4[2] = 0u; bb.u4[3] = 0u;
            float4v d = __builtin_amdgcn_mfma_f32_16x16x32_bf16(wu2r, bb.s8, z4, 0, 0, 0);
            // delta: pixel (pyc,pxc), channels och..och+3 -> one b64 write
            uint2 dv;
            dv.x = pack2(d[0] + bu24[0], d[1] + bu24[1]);
            dv.y = pack2(d[2] + bu24[2], d[3] + bu24[3]);
            if (!interior) {
                int gy = gy0 - 1 + pyc, gx = gx0 - 1 + pxc;
                bool im = ((unsigned)gy < 256u) & ((unsigned)gx < 256u);
                if (!im) { dv.x = 0u; dv.y = 0u; }   // ref zero-pads outside
            }
            if (vld)
                *(uint2*)(comb + ((pyc + 1) * 20 + (pxc + 1)) * PIT + och) = dv;
            // increment pixel index by 64: +3 rows +10 cols (mod 18)
            raw += 64; px += 10; py += 3;
            if (px >= 18) { px -= 18; py += 1; }
        }
    }
    __syncthreads();

    // ---- stage C: tau conv (D[ch][pix], K=32 [delta||state]) + x via MFMA --
    // Tap-row register cache: Ta = row g+1, Tb = row g+2 (dx = 0..2, chunk q);
    // per iteration load only the fresh row g+3, then rotate.
    {
        const int w4 = w * 4;
#define LDROW(r, dx) (*(const short8*)(comb + (((r) * 20) + (m + 1 + (dx))) * PIT + q * 8))
        short8 Ta0 = LDROW(w4 + 1, 0), Ta1 = LDROW(w4 + 1, 1), Ta2 = LDROW(w4 + 1, 2);
        short8 Tb0 = LDROW(w4 + 2, 0), Tb1 = LDROW(w4 + 2, 1), Tb2 = LDROW(w4 + 2, 2);
#pragma unroll
        for (int i = 0; i < 4; ++i) {
            int g = w4 + i;                      // core row; pixel col = m
            short8 Tc0 = LDROW(g + 3, 0), Tc1 = LDROW(g + 3, 1), Tc2 = LDROW(g + 3, 2);
            // xp taps 0..7 for the 10th MFMA (window base = core-(1,1))
            short8 bx = *(const short8*)(comb + ((g + 1) * 20 + (m + 1)) * PIT + 32);
            float4v acc = z4;
            __builtin_amdgcn_s_setprio(1);
            acc = __builtin_amdgcn_mfma_f32_16x16x32_bf16(wtnr[0], Ta0, acc, 0, 0, 0);
            acc = __builtin_amdgcn_mfma_f32_16x16x32_bf16(wtnr[1], Ta1, acc, 0, 0, 0);
            acc = __builtin_amdgcn_mfma_f32_16x16x32_bf16(wtnr[2], Ta2, acc, 0, 0, 0);
            acc = __builtin_amdgcn_mfma_f32_16x16x32_bf16(wtnr[3], Tb0, acc, 0, 0, 0);
            acc = __builtin_amdgcn_mfma_f32_16x16x32_bf16(wtnr[4], Tb1, acc, 0, 0, 0);
            acc = __builtin_amdgcn_mfma_f32_16x16x32_bf16(wtnr[5], Tb2, acc, 0, 0, 0);
            acc = __builtin_amdgcn_mfma_f32_16x16x32_bf16(wtnr[6], Tc0, acc, 0, 0, 0);
            acc = __builtin_amdgcn_mfma_f32_16x16x32_bf16(wtnr[7], Tc1, acc, 0, 0, 0);
            acc = __builtin_amdgcn_mfma_f32_16x16x32_bf16(wtnr[8], Tc2, acc, 0, 0, 0);
            acc = __builtin_amdgcn_mfma_f32_16x16x32_bf16(wtxr,   bx,  acc, 0, 0, 0);
            __builtin_amdgcn_s_setprio(0);
            int gy = gy0 + g;
            const size_t pix = pb + gy * 256 + gx0 + m;
            const ushort_t* cpx = comb + ((g + 2) * 20 + (m + 2)) * PIT;
            // tap 8 = x[core+(1,1)] = tap0 (ch32) of window based at (g+3,m+3)
            float x8c = bu2f(comb[((g + 3) * 20 + (m + 3)) * PIT + 32]);
            uint2 su = *(const uint2*)(cpx + 16 + och);        // state och..+3
            uint2 du = *(const uint2*)(cpx + och);             // delta
            float sold[4] = { lo2f(su.x), hi2f(su.x), lo2f(su.y), hi2f(su.y) };
            float dvv[4]  = { lo2f(du.x), hi2f(du.x), lo2f(du.y), hi2f(du.y) };
            float sn[4];
#pragma unroll
            for (int r = 0; r < 4; ++r) {
                float tl  = acc[r] + tb4[r] + x8c * wtx84[r];
                float e   = __expf(-tl);
                float bta = __builtin_amdgcn_rcpf(1.f + e);
                bta = fminf(fmaxf(bta, 0.01f), 0.99f);
                sn[r] = dvv[r] + bta * (sold[r] - dvv[r]);
            }
            if (!last) {
                uint2 o;
                o.x = pack2(sn[0], sn[1]); o.y = pack2(sn[2], sn[3]);
                *(uint2*)(stOut + pix * 16 + och) = o;         // b64 store
            } else {
                // fused readout: channels spread over q -> butterfly on q bits
                float v = sn[0] * wr4[0] + sn[1] * wr4[1]
                        + sn[2] * wr4[2] + sn[3] * wr4[3];
                v += __shfl_xor(v, 16);
                v += __shfl_xor(v, 32);
                if (q == 0) {
                    float eo = __expf(-(v + br));
                    outg[pix] = __builtin_amdgcn_rcpf(1.f + eo);
                }
            }
            // rotate the row cache
            Ta0 = Tb0; Ta1 = Tb1; Ta2 = Tb2;
            Tb0 = Tc0; Tb1 = Tc1; Tb2 = Tc2;
        }
#undef LDROW
    }
}

// ---------------------------------------------------------------------------
extern "C" void kernel_launch(void* const* d_in, const int* in_sizes, int n_in,
                              void* d_out, int out_size, void* d_ws, size_t ws_size,
                              hipStream_t stream)
{
    const float* x          = (const float*)d_in[0];
    const float* w_perceive = (const float*)d_in[1];
    const float* b_perceive = (const float*)d_in[2];
    const float* w_up1      = (const float*)d_in[3];
    const float* b_up1      = (const float*)d_in[4];
    const float* w_up2      = (const float*)d_in[5];
    const float* b_up2      = (const float*)d_in[6];
    const float* w_tau      = (const float*)d_in[7];
    const float* b_tau_conv = (const float*)d_in[8];
    const float* b_tau      = (const float*)d_in[9];
    const float* w_read     = (const float*)d_in[10];
    const float* b_read     = (const float*)d_in[11];
    // d_in[12] = n_steps = 10 (host-known; hard-coded for graph capture)
    float* out = (float*)d_out;

    const size_t stateElems = (size_t)B_ * H_ * W_ * 16;     // 33,554,432 bf16
    const size_t xp8Elems   = (size_t)B_ * XPP * XPP * 8;    // 17,305,600 bf16

    // ws layout (~170 MB; tx tensor deleted)
    ushort_t* stA  = (ushort_t*)d_ws;
    ushort_t* stB  = stA + stateElems;
    ushort_t* xp8g = stB + stateElems;         // 34.6 MB
    ushort_t* wh1p = xp8g + xp8Elems;          // 2560
    ushort_t* wu2f = wh1p + 2560;              // 512
    ushort_t* wtxf = wu2f + 512;               // 512
    ushort_t* wtn  = wtxf + 512;               // 4608
    float*    scal = (float*)(wtn + 4608);     // 64 floats

    const size_t needBytes = (2 * stateElems + xp8Elems
                              + 2560 + 512 + 512 + 4608) * sizeof(ushort_t)
                           + 64 * sizeof(float);
    if (ws_size < needBytes) return;

    prep<<<dim3(1), dim3(256), 0, stream>>>(
        w_perceive, w_up1, b_up1, b_perceive, w_up2, w_tau,
        b_tau_conv, b_tau, wh1p, wu2f, wtxf, wtn, scal);
    precompute_xp8<<<dim3((B_ * XPP * XPP + 255) / 256), dim3(256), 0, stream>>>(
        x, xp8g);

    ushort_t* cur = stA;
    ushort_t* nxt = stB;
    for (int s = 0; s < 10; ++s) {
        nca_step<<<dim3(16, 16, 32), dim3(256), 0, stream>>>(
            cur, nxt, xp8g, wh1p, wu2f, wtxf, wtn, scal, b_up2,
            w_read, b_read, out, (s == 0) ? 1 : 0, (s == 9) ? 1 : 0);
        ushort_t* t = cur; cur = nxt; nxt = t;
    }
}